// Round 8
// baseline (197.476 us; speedup 1.0000x reference)
//
#include <hip/hip_runtime.h>
#include <hip/hip_bf16.h>

// TAttention: B=16, C=32, N=1024, T=128, R=10
//  K1 k_reduce_c : k[b,n,t] = sum_c alpha[c]*x[b,c,n,t]      (256 MB read, BW)
//  K2 kw_partial2: p_w partials                              (8 MB, fast)
//  K2.5 kw_reduce: kwc[b][w][r][t]                           (tiny)
//  K3 scores_softmax: att[b][t][s] bf16                      (tiny)
//  K4 out_gemm5  : att once in LDS (32KB swizzled); x B-frags DIRECT
//     global->reg, ping-pong 1 slab ahead; NO x LDS, NO loop barriers.
//     Wave = 16 n-rows x 128 t -> no duplicate x reads, 8 float4/lane/slab.
// R7 lesson: barrier scheme irrelevant; K4 was duty-cycle-bound (loads in
// flight only ~20% of slab period). Fix = loads continuously outstanding.

#define B_ 16
#define C_ 32
#define N_ 1024
#define T_ 128
#define R_ 10

typedef __bf16 bf16x8 __attribute__((ext_vector_type(8)));
typedef __bf16 bf16x4 __attribute__((ext_vector_type(4)));
typedef float f32x4 __attribute__((ext_vector_type(4)));

__device__ __forceinline__ void lds_barrier() {
    asm volatile("s_waitcnt lgkmcnt(0)" ::: "memory");
    __builtin_amdgcn_s_barrier();
    asm volatile("" ::: "memory");
}

// ---------------------------------------------------------------- kernel 1
__global__ __launch_bounds__(256) void k_reduce_c(const float* __restrict__ x,
                                                  const float* __restrict__ alpha,
                                                  float* __restrict__ k) {
    int bid = blockIdx.x;            // B * N/8 = 2048
    int b   = bid >> 7;
    int nc  = bid & 127;
    int tid = threadIdx.x;
    int nl  = tid >> 5;
    int lc  = tid & 31;
    int n   = nc * 8 + nl;
    const float4* xb = reinterpret_cast<const float4*>(
        x + ((size_t)(b * C_) * N_ + n) * T_) + lc;
    float4 acc = {0.f, 0.f, 0.f, 0.f};
    #pragma unroll 8
    for (int c = 0; c < C_; ++c) {
        float a = alpha[c];
        float4 v = xb[(size_t)c * (N_ * T_ / 4)];
        acc.x += a * v.x; acc.y += a * v.y; acc.z += a * v.z; acc.w += a * v.w;
    }
    reinterpret_cast<float4*>(k + ((size_t)b * N_ + n) * T_)[lc] = acc;
}

// ---------------------------------------------------------------- kernel 2
__global__ __launch_bounds__(128) void kw_partial2(const float* __restrict__ k,
                                                   const float* __restrict__ W1,
                                                   const float* __restrict__ W2,
                                                   float* __restrict__ p1,
                                                   float* __restrict__ p2) {
    __shared__ float wl[32][20];
    int bid = blockIdx.x;            // b*32 + ch
    int b   = bid >> 5;
    int ch  = bid & 31;
    int n0  = ch * 32;
    int t   = threadIdx.x;
    for (int i = t; i < 32 * 20; i += 128) {
        int nl = i & 31, q = i >> 5;
        wl[nl][q] = (q < 10) ? W1[q * N_ + n0 + nl] : W2[(q - 10) * N_ + n0 + nl];
    }
    __syncthreads();
    float a1[R_] = {}, a2[R_] = {};
    const float* kb = k + ((size_t)b * N_ + n0) * T_ + t;
    #pragma unroll 2
    for (int g = 0; g < 4; ++g) {
        float kv[8];
        #pragma unroll
        for (int j = 0; j < 8; ++j) kv[j] = kb[(g * 8 + j) * T_];
        #pragma unroll
        for (int j = 0; j < 8; ++j) {
            int nl = g * 8 + j;
            #pragma unroll
            for (int r = 0; r < R_; ++r) {
                a1[r] += kv[j] * wl[nl][r];
                a2[r] += kv[j] * wl[nl][10 + r];
            }
        }
    }
    #pragma unroll
    for (int r = 0; r < R_; ++r) {
        size_t o = (((size_t)b * R_ + r) * 32 + ch) * T_ + t;
        p1[o] = a1[r];
        p2[o] = a2[r];
    }
}

// ---------------------------------------------------------------- kernel 2.5
__global__ __launch_bounds__(128) void kw_reduce(const float* __restrict__ p1,
                                                 const float* __restrict__ p2,
                                                 float* __restrict__ kwc) {
    int bid = blockIdx.x;            // b*20 + w*10 + r
    int b = bid / 20;
    int q = bid - b * 20;
    int w = q / 10;
    int r = q - w * 10;
    int t = threadIdx.x;
    const float* src = (w ? p2 : p1) + (((size_t)b * R_ + r) * 32) * T_ + t;
    float s = 0.f;
    #pragma unroll
    for (int ch = 0; ch < 32; ++ch) s += src[ch * T_];
    kwc[(((size_t)b * 2 + w) * R_ + r) * T_ + t] = s;
}

// ---------------------------------------------------------------- kernel 3
__global__ __launch_bounds__(128) void scores_softmax(const float* __restrict__ kwc,
                                                      __bf16* __restrict__ att) {
    __shared__ __align__(16) float kw1s[T_][12];
    __shared__ __align__(16) float kw2s[T_][12];
    __shared__ float sc[T_][T_ + 1];
    int b = blockIdx.x;
    int t = threadIdx.x;
    const float* kb = kwc + (size_t)b * 2 * R_ * T_;
    #pragma unroll
    for (int r = 0; r < R_; ++r) {
        kw1s[t][r] = kb[r * T_ + t];
        kw2s[t][r] = kb[(R_ + r) * T_ + t];
    }
    __syncthreads();
    float myw[R_];
    #pragma unroll
    for (int r = 0; r < R_; ++r) myw[r] = kw1s[t][r];
    float mx = -1e30f;
    for (int s = 0; s < T_; ++s) {
        float wv[12];
        const float4* qr = reinterpret_cast<const float4*>(&kw2s[s][0]);
        #pragma unroll
        for (int q = 0; q < 3; ++q) *reinterpret_cast<float4*>(&wv[q * 4]) = qr[q];
        float v = 0.f;
        #pragma unroll
        for (int r = 0; r < R_; ++r) v += myw[r] * wv[r];
        sc[t][s] = v;
        mx = fmaxf(mx, v);
    }
    float sum = 0.f;
    for (int s = 0; s < T_; ++s) {
        float e = __expf(sc[t][s] - mx);
        sc[t][s] = e;
        sum += e;
    }
    float inv = 1.0f / sum;
    __bf16* arow = att + ((size_t)b * T_ + t) * T_;
    for (int s8 = 0; s8 < T_; s8 += 8) {
        bf16x8 hv;
        #pragma unroll
        for (int q = 0; q < 8; ++q) hv[q] = (__bf16)(sc[t][s8 + q] * inv);
        *reinterpret_cast<bf16x8*>(arow + s8) = hv;
    }
}

// ---------------------------------------------------------------- kernel 4
// block = (b,c,4 slabs); wave w owns n-rows [w*16, w*16+16) x all t.
// att in LDS (only barrier = prologue). x frags global->reg, 1 slab ahead.
#define SLAB_BODY(XCUR, XNXT, I)                                              \
    {                                                                         \
        bf16x8 bx[4];                                                         \
        _Pragma("unroll")                                                     \
        for (int ks = 0; ks < 4; ++ks) {                                      \
            float4 lo = XCUR[2 * ks], hi = XCUR[2 * ks + 1];                  \
            bx[ks] = (bf16x8){(__bf16)lo.x, (__bf16)lo.y, (__bf16)lo.z,       \
                              (__bf16)lo.w, (__bf16)hi.x, (__bf16)hi.y,       \
                              (__bf16)hi.z, (__bf16)hi.w};                    \
        }                                                                     \
        if ((I) < 3) {                                                        \
            const float* xr = xrow + (size_t)((I) + 1) * 64 * T_;             \
            _Pragma("unroll")                                                 \
            for (int q = 0; q < 8; ++q)                                       \
                XNXT[q] = *reinterpret_cast<const float4*>(                   \
                    xr + (q >> 1) * 32 + (q & 1) * 4);                        \
        }                                                                     \
        f32x4 acc[8] = {};                                                    \
        _Pragma("unroll")                                                     \
        for (int ks = 0; ks < 4; ++ks) {                                      \
            int kc = ks * 64 + g * 16;                                        \
            bf16x8 a[8];                                                      \
            _Pragma("unroll")                                                 \
            for (int tt = 0; tt < 8; ++tt)                                    \
                a[tt] = *reinterpret_cast<const bf16x8*>(                     \
                    attb + (tt * 16 + r16) * 256 + (kc ^ swz));               \
            _Pragma("unroll")                                                 \
            for (int tt = 0; tt < 8; ++tt)                                    \
                acc[tt] = __builtin_amdgcn_mfma_f32_16x16x32_bf16(            \
                    a[tt], bx[ks], acc[tt], 0, 0, 0);                         \
        }                                                                     \
        float* o = out + slab0 + (size_t)((I) * 64 + wave * 16 + r16) * T_;   \
        _Pragma("unroll")                                                     \
        for (int tt = 0; tt < 8; ++tt)                                        \
            *reinterpret_cast<f32x4*>(o + tt * 16 + g * 4) = acc[tt];         \
    }

__global__ __launch_bounds__(256, 3) void out_gemm5(const float* __restrict__ x,
                                                    const __bf16* __restrict__ att,
                                                    float* __restrict__ out) {
    __shared__ __align__(16) __bf16 attl[T_][T_];   // 32 KB swizzled
    int bid = blockIdx.x;            // b*128 + c*4 + sg
    int sg  = bid & 3;
    int c   = (bid >> 2) & 31;
    int b   = bid >> 7;
    int tid = threadIdx.x;
    char* attb = (char*)&attl[0][0];
    size_t slab0 = ((size_t)(b * C_ + c) * N_ + sg * 256) * T_;

    // att loads FIRST (LDS write waits only these; x0 loads keep flying)
    const uint4* ga = reinterpret_cast<const uint4*>(att + (size_t)b * T_ * T_);
    uint4 ar[8];
    #pragma unroll
    for (int i = 0; i < 8; ++i) ar[i] = ga[i * 256 + tid];

    int wave = tid >> 6, lane = tid & 63;
    int r16 = lane & 15, g = lane >> 4;
    int swz = (r16 & 7) << 4;
    const float* xrow = x + slab0 + (size_t)(wave * 16 + r16) * T_ + g * 8;

    float4 xa[8], xb[8];
    #pragma unroll
    for (int q = 0; q < 8; ++q)      // slab 0: frag (ks=q>>1, half=q&1)
        xa[q] = *reinterpret_cast<const float4*>(xrow + (q >> 1) * 32 + (q & 1) * 4);

    #pragma unroll
    for (int i = 0; i < 8; ++i) {
        int e = i * 256 + tid, row = e >> 4;
        int bc = ((e & 15) * 16) ^ ((row & 7) << 4);
        *reinterpret_cast<uint4*>(attb + row * 256 + bc) = ar[i];
    }
    lds_barrier();

    SLAB_BODY(xa, xb, 0)
    SLAB_BODY(xb, xa, 1)
    SLAB_BODY(xa, xb, 2)
    SLAB_BODY(xb, xa, 3)
}

// ----------------------------------------------------------------
extern "C" void kernel_launch(void* const* d_in, const int* in_sizes, int n_in,
                              void* d_out, int out_size, void* d_ws, size_t ws_size,
                              hipStream_t stream) {
    const float* x     = (const float*)d_in[0];
    const float* W1    = (const float*)d_in[1];
    const float* W2    = (const float*)d_in[2];
    const float* alpha = (const float*)d_in[3];
    float* out = (float*)d_out;

    float* k    = (float*)d_ws;                         // 8 MB
    float* p1   = k   + (size_t)B_ * N_ * T_;           // [b][r][32][t]
    float* p2   = p1  + (size_t)B_ * R_ * 32 * T_;
    float* kwc  = p2  + (size_t)B_ * R_ * 32 * T_;      // [b][2][r][t]
    __bf16* att = (__bf16*)(kwc + (size_t)B_ * 2 * R_ * T_);  // [b][t][s]

    k_reduce_c   <<<dim3(B_ * (N_ / 8)), dim3(256), 0, stream>>>(x, alpha, k);
    kw_partial2  <<<dim3(B_ * 32),       dim3(128), 0, stream>>>(k, W1, W2, p1, p2);
    kw_reduce    <<<dim3(B_ * 20),       dim3(128), 0, stream>>>(p1, p2, kwc);
    scores_softmax<<<dim3(B_),           dim3(128), 0, stream>>>(kwc, att);
    out_gemm5    <<<dim3(B_ * C_ * 4),   dim3(256), 0, stream>>>(x, att, out);
}